// Round 11
// baseline (365.372 us; speedup 1.0000x reference)
//
#include <hip/hip_runtime.h>
#include <cstdint>
#include <cstddef>

#define CC 256
#define NN 16
#define LL 4096
#define CLEN 32
#define NBLK 512
#define LOG2E 1.4426950408889634f

typedef __attribute__((ext_vector_type(8))) short short8;
typedef __attribute__((ext_vector_type(4))) float f32x4;

__device__ __forceinline__ float softplus_f(float z) {
    return fmaxf(z, 0.f) + log1pf(expf(-fabsf(z)));
}

__device__ __forceinline__ uint32_t pack_bf2(float d, float u) {
    uint32_t lo = (__float_as_uint(d) + 0x8000u) >> 16;
    uint32_t hh = (__float_as_uint(u) + 0x8000u) & 0xffff0000u;
    return hh | lo;
}

__device__ __forceinline__ short bf16r(float f) {
    return (short)((__float_as_uint(f) + 0x8000u) >> 16);
}

// Device-scope grid barrier, one-shot counter per barrier instance (4 used).
// atomicAdd on global = device scope (m20); __threadfence = agent-scope
// release/acquire (handles cross-XCD L2 non-coherence). Spin cap = safety
// valve against a hang if co-residency were ever violated.
// Co-residency: LDS 68KB -> hard max 2 blk/CU; __launch_bounds__(256,2)
// caps VGPR at 256 -> 8 waves/CU -> all 512 blocks resident. REQUIRED.
__device__ __forceinline__ void gbar(uint32_t* cnt) {
    __syncthreads();
    if (threadIdx.x == 0) {
        __threadfence();
        atomicAdd(cnt, 1u);
        int spins = 0;
        while (atomicAdd(cnt, 0u) < (uint32_t)NBLK) {
            __builtin_amdgcn_s_sleep(16);
            if (++spins > (1 << 26)) break;   // ~safety valve; never expected
        }
        __threadfence();
    }
    __syncthreads();
}

// LDS union, 68 KB -> exactly 2 blocks/CU -> 512 blocks co-resident.
// Phase A uses .k1; phases B/D share .ps (B stages, D REUSES residents);
// phase C uses no LDS; phase E uses .tile.
union Smem {
    struct { short A[32][264]; short B[64][264]; short WB[16][264]; short WC[16][264]; } k1;
    struct { float bm[CLEN * NN]; float cm[CLEN * NN]; uint32_t w[CLEN * 256]; float y[CLEN * 256]; } ps;
    float tile[64 * 65];
};

// One fused kernel (plain launch + atomic grid barriers), 5 phases:
//  A: k1 MFMA (2 tiles/block)   -> du, Bm, Cm
//  B: p1 chunk aggregates        -> P, S       (sW/sBm/sCm stay resident!)
//  C: p2 chunk-scan (gtid<32768) -> Hin        (no LDS)
//  D: p3 replay (NO du re-read: sW/sBm/sCm still in LDS from B) -> yAB, yC
//  E: k6 transpose-reduce        -> out
__global__ __launch_bounds__(256, 2) void fused_all(
    const float* __restrict__ feat, const float* __restrict__ A_log,
    const float* __restrict__ Dv, const float* __restrict__ Wd,
    const float* __restrict__ bd, const float* __restrict__ WB,
    const float* __restrict__ WC, float* __restrict__ out,
    uint32_t* __restrict__ du, float* __restrict__ Bm, float* __restrict__ Cm,
    float* __restrict__ P, float* __restrict__ S, float* __restrict__ Hin,
    float* __restrict__ yAB, float* __restrict__ yC, uint32_t* __restrict__ bar)
{
    __shared__ Smem sm;
    int t    = threadIdx.x;
    int lane = t & 63;
    int wq   = t >> 6;
    int m    = lane & 15;
    int quad = lane >> 4;
    int m0   = (wq & 1) * 16;
    int n0   = (wq >> 1) * 32;

    // ================= Phase A: k1 MFMA, 2 tiles per block =================
    for (int it = 0; it < 2; ++it) {
        __syncthreads();                      // protect LDS reuse across iters
        int blk = it * 512 + blockIdx.x;      // b*512 + lt*4 + ct
        int b  = blk >> 9;
        int lt = (blk >> 2) & 127;
        int ct = blk & 3;
        int l0 = lt * 32, c0 = ct * 64;
        const float* fbase = feat + (size_t)b * CC * LL;
        bool doBC = (ct == 0);

        #pragma unroll
        for (int p = 0; p < 8; ++p) {         // stage A: [l][k], coalesced on l
            int k  = p * 32 + (t >> 3);
            int lc = (t & 7) * 4;
            f32x4 v = *(const f32x4*)&fbase[(size_t)k * LL + l0 + lc];
            #pragma unroll
            for (int i = 0; i < 4; ++i) sm.k1.A[lc + i][k] = bf16r(v[i]);
        }
        #pragma unroll
        for (int p = 0; p < 16; ++p) {        // stage B: [c][k], coalesced on c
            int k  = p * 16 + (t >> 4);
            int cc = (t & 15) * 4;
            f32x4 v = *(const f32x4*)&Wd[(size_t)k * CC + c0 + cc];
            #pragma unroll
            for (int i = 0; i < 4; ++i) sm.k1.B[cc + i][k] = bf16r(v[i]);
        }
        if (doBC) {
            #pragma unroll
            for (int p = 0; p < 4; ++p) {
                int k  = p * 64 + (t >> 2);
                int nc = (t & 3) * 4;
                f32x4 vb = *(const f32x4*)&WB[(size_t)k * NN + nc];
                f32x4 vc = *(const f32x4*)&WC[(size_t)k * NN + nc];
                #pragma unroll
                for (int i = 0; i < 4; ++i) {
                    sm.k1.WB[nc + i][k] = bf16r(vb[i]);
                    sm.k1.WC[nc + i][k] = bf16r(vc[i]);
                }
            }
        }
        __syncthreads();

        f32x4 acc0 = {0.f, 0.f, 0.f, 0.f};
        f32x4 acc1 = {0.f, 0.f, 0.f, 0.f};
        f32x4 accB = {0.f, 0.f, 0.f, 0.f};
        const short (*sWsel)[264] = (wq >> 1) ? sm.k1.WC : sm.k1.WB;
        for (int ks = 0; ks < 8; ++ks) {
            int k8 = ks * 32 + quad * 8;
            short8 af  = *(const short8*)&sm.k1.A[m0 + m][k8];
            short8 bf0 = *(const short8*)&sm.k1.B[n0 + m][k8];
            short8 bf1 = *(const short8*)&sm.k1.B[n0 + 16 + m][k8];
            acc0 = __builtin_amdgcn_mfma_f32_16x16x32_bf16(af, bf0, acc0, 0, 0, 0);
            acc1 = __builtin_amdgcn_mfma_f32_16x16x32_bf16(af, bf1, acc1, 0, 0, 0);
            if (doBC) {
                short8 bbf = *(const short8*)&sWsel[m][k8];
                accB = __builtin_amdgcn_mfma_f32_16x16x32_bf16(af, bbf, accB, 0, 0, 0);
            }
        }
        if (doBC) {
            float* dst = (wq >> 1) ? Cm : Bm;
            #pragma unroll
            for (int r = 0; r < 4; ++r) {
                int l = l0 + m0 + quad * 4 + r;
                dst[((size_t)b * LL + l) * NN + m] = accB[r];
            }
        }
        float bd0 = bd[c0 + n0 + m];
        float bd1 = bd[c0 + n0 + 16 + m];
        int cA = c0 + n0 + m;
        int cB = cA + 16;
        int lb = l0 + m0 + quad * 4;
        f32x4 xv0 = *(const f32x4*)&fbase[(size_t)cA * LL + lb];
        f32x4 xv1 = *(const f32x4*)&fbase[(size_t)cB * LL + lb];
        #pragma unroll
        for (int r = 0; r < 4; ++r) {
            float d0 = softplus_f(acc0[r] + bd0);
            float d1 = softplus_f(acc1[r] + bd1);
            du[((size_t)b * LL + lb + r) * CC + cA] = pack_bf2(d0, d0 * xv0[r]);
            du[((size_t)b * LL + lb + r) * CC + cB] = pack_bf2(d1, d1 * xv1[r]);
        }
    }

    gbar(bar + 0);   // du/Bm/Cm visible grid-wide

    // ================= A2 (used by phases B and D) =================
    int c = t;
    float A2[NN];
    {
        const float4* al = (const float4*)(A_log + c * NN);
        #pragma unroll
        for (int q = 0; q < 4; ++q) {
            float4 v = al[q];
            A2[q*4+0] = -expf(v.x) * LOG2E;
            A2[q*4+1] = -expf(v.y) * LOG2E;
            A2[q*4+2] = -expf(v.z) * LOG2E;
            A2[q*4+3] = -expf(v.w) * LOG2E;
        }
    }

    // ================= Phase B: p1 chunk aggregates =================
    int blk = blockIdx.x;                    // 0..511
    int b1  = (blk >> 7) & 1;
    int ch  = blk & 127;
    bool isRow = (blk < 256);
    int p0, inner;
    if (isRow) { p0 = 32 * ch;                              inner = 1;  }
    else       { p0 = 63 - (ch >> 1) + 2048 * (ch & 1);     inner = 64; }

    for (int i = t; i < CLEN * NN; i += 256) {   // stage sBm AND sCm (D needs both)
        int j = i >> 4, nn = i & 15;
        size_t o = ((size_t)b1 * LL + (p0 + inner * j)) * NN + nn;
        sm.ps.bm[i] = Bm[o];
        sm.ps.cm[i] = Cm[o];
    }
    {
        const uint32_t* dub = du + (size_t)b1 * LL * CC + c;
        uint32_t wt[CLEN];
        #pragma unroll
        for (int j = 0; j < CLEN; ++j) wt[j] = dub[(size_t)(p0 + inner * j) * CC];
        #pragma unroll
        for (int j = 0; j < CLEN; ++j) sm.ps.w[j * 256 + c] = wt[j];
    }
    __syncthreads();

    if (isRow) {
        float Sf[NN] = {}, Sr[NN] = {}, pref[NN];
        #pragma unroll
        for (int nn = 0; nn < NN; ++nn) pref[nn] = 1.f;
        float sumd = 0.f;
        #pragma unroll 1
        for (int j = 0; j < CLEN; ++j) {
            uint32_t wj = sm.ps.w[j * 256 + c];
            float dx = __uint_as_float(wj << 16);
            float uy = __uint_as_float(wj & 0xffff0000u);
            sumd += dx;
            float dA[NN];
            #pragma unroll
            for (int nn = 0; nn < NN; ++nn) dA[nn] = __builtin_amdgcn_exp2f(A2[nn] * dx);
            #pragma unroll
            for (int nn = 0; nn < NN; ++nn) {
                float Bu = uy * sm.ps.bm[j * 16 + nn];
                Sf[nn] = fmaf(dA[nn], Sf[nn], Bu);
                Sr[nn] = fmaf(pref[nn], Bu, Sr[nn]);
                pref[nn] *= dA[nn];
            }
        }
        size_t base0 = ((size_t)(b1 * 128 + ch)) * 4096 + (size_t)c * 16;
        size_t base1 = ((size_t)((2 + b1) * 128 + (127 - ch))) * 4096 + (size_t)c * 16;
        #pragma unroll
        for (int nn = 0; nn < NN; ++nn) {
            P[base0 + nn] = __builtin_amdgcn_exp2f(A2[nn] * sumd);
            S[base0 + nn] = Sf[nn];
            S[base1 + nn] = Sr[nn];
        }
    } else {
        float Sv[NN] = {};
        float sumd = 0.f;
        #pragma unroll 1
        for (int j = 0; j < CLEN; ++j) {
            uint32_t wj = sm.ps.w[j * 256 + c];
            float dx = __uint_as_float(wj << 16);
            float uy = __uint_as_float(wj & 0xffff0000u);
            sumd += dx;
            float dA[NN];
            #pragma unroll
            for (int nn = 0; nn < NN; ++nn) dA[nn] = __builtin_amdgcn_exp2f(A2[nn] * dx);
            #pragma unroll
            for (int nn = 0; nn < NN; ++nn)
                Sv[nn] = fmaf(dA[nn], Sv[nn], uy * sm.ps.bm[j * 16 + nn]);
        }
        size_t base = ((size_t)((4 + b1) * 128 + ch)) * 4096 + (size_t)c * 16;
        #pragma unroll
        for (int nn = 0; nn < NN; ++nn) {
            P[base + nn] = __builtin_amdgcn_exp2f(A2[nn] * sumd);
            S[base + nn] = Sv[nn];
        }
    }

    gbar(bar + 1);   // P/S visible; LDS (.ps) untouched by phase C

    // ================= Phase C: p2 chunk-scan (no LDS) =================
    {
        int gid = blockIdx.x * 256 + t;
        if (gid < 32768) {
            int cn = gid & 4095;
            int db = gid >> 12;
            int d = db >> 1;
            int cls = (d == 1) ? 1 : ((d == 3) ? 2 : 0);
            int bb = db & 1;
            const size_t sbase = ((size_t)(cls * 2 + bb) * 128) * 4096 + cn;
            const size_t pbase = (d == 1) ? (((size_t)bb * 128) * 4096 + cn) : sbase;
            const size_t obase = ((size_t)db * 128) * 4096 + cn;
            float h = 0.f;
            for (int g = 0; g < 16; ++g) {
                float pv[8], sv[8];
                #pragma unroll
                for (int i = 0; i < 8; ++i) {
                    int cc = g * 8 + i;
                    int chm = (d == 2) ? (126 - 2 * (cc >> 1) + (cc & 1)) : cc;
                    int chp = (d == 1) ? (127 - cc) : chm;
                    pv[i] = P[pbase + (size_t)chp * 4096];
                    sv[i] = S[sbase + (size_t)chm * 4096];
                }
                #pragma unroll
                for (int i = 0; i < 8; ++i) {
                    Hin[obase + (size_t)(g * 8 + i) * 4096] = h;
                    h = fmaf(pv[i], h, sv[i]);
                }
            }
        }
    }

    gbar(bar + 2);   // Hin visible; sW/sBm/sCm STILL resident from phase B

    // ================= Phase D: p3 replay (reuses resident LDS) =================
    if (isRow) {
        // backward d1 first (only h1 live), y1 -> LDS own slot
        int chr = 127 - ch;
        float h1[NN];
        {
            const float4* hp1 = (const float4*)(Hin + ((size_t)(1 * 2 + b1) * 128 + chr) * 4096 + (size_t)c * 16);
            #pragma unroll
            for (int q = 0; q < 4; ++q) {
                float4 v1 = hp1[q];
                h1[q*4+0]=v1.x; h1[q*4+1]=v1.y; h1[q*4+2]=v1.z; h1[q*4+3]=v1.w;
            }
        }
        #pragma unroll 1
        for (int j = CLEN - 1; j >= 0; --j) {
            uint32_t wj = sm.ps.w[j * 256 + c];
            float dx = __uint_as_float(wj << 16);
            float uy = __uint_as_float(wj & 0xffff0000u);
            float dA[NN];
            #pragma unroll
            for (int nn = 0; nn < NN; ++nn) dA[nn] = __builtin_amdgcn_exp2f(A2[nn] * dx);
            float yv = 0.f;
            #pragma unroll
            for (int nn = 0; nn < NN; ++nn) {
                float Bu = uy * sm.ps.bm[j * 16 + nn];
                h1[nn] = fmaf(dA[nn], h1[nn], Bu);
                yv = fmaf(h1[nn], sm.ps.cm[j * 16 + nn], yv);
            }
            sm.ps.y[j * 256 + c] = yv;    // own slot; no barrier needed
        }
        // forward d0 + d2
        int ch2 = 126 - (ch & ~1) + (ch & 1);
        float h0[NN], h2[NN];
        {
            const float4* hp0 = (const float4*)(Hin + ((size_t)(0 * 2 + b1) * 128 + ch)  * 4096 + (size_t)c * 16);
            const float4* hp2 = (const float4*)(Hin + ((size_t)(2 * 2 + b1) * 128 + ch2) * 4096 + (size_t)c * 16);
            #pragma unroll
            for (int q = 0; q < 4; ++q) {
                float4 v0 = hp0[q], v2 = hp2[q];
                h0[q*4+0]=v0.x; h0[q*4+1]=v0.y; h0[q*4+2]=v0.z; h0[q*4+3]=v0.w;
                h2[q*4+0]=v2.x; h2[q*4+1]=v2.y; h2[q*4+2]=v2.z; h2[q*4+3]=v2.w;
            }
        }
        #pragma unroll 1
        for (int j = 0; j < CLEN; ++j) {
            uint32_t wj = sm.ps.w[j * 256 + c];
            float dx = __uint_as_float(wj << 16);
            float uy = __uint_as_float(wj & 0xffff0000u);
            float dA[NN];
            #pragma unroll
            for (int nn = 0; nn < NN; ++nn) dA[nn] = __builtin_amdgcn_exp2f(A2[nn] * dx);
            float y0v = 0.f, y2v = 0.f;
            #pragma unroll
            for (int nn = 0; nn < NN; ++nn) {
                float Bu = uy * sm.ps.bm[j * 16 + nn];
                float cm = sm.ps.cm[j * 16 + nn];
                h0[nn] = fmaf(dA[nn], h0[nn], Bu);
                h2[nn] = fmaf(dA[nn], h2[nn], Bu);
                y0v = fmaf(h0[nn], cm, y0v);
                y2v = fmaf(h2[nn], cm, y2v);
            }
            yAB[((size_t)b1 * LL + p0 + j) * CC + c] = 0.25f * (y0v + y2v + sm.ps.y[j * 256 + c]);
        }
    } else {
        float h[NN];
        {
            const float4* hp = (const float4*)(Hin + ((size_t)(3 * 2 + b1) * 128 + ch) * 4096 + (size_t)c * 16);
            #pragma unroll
            for (int q = 0; q < 4; ++q) {
                float4 v = hp[q];
                h[q*4+0]=v.x; h[q*4+1]=v.y; h[q*4+2]=v.z; h[q*4+3]=v.w;
            }
        }
        #pragma unroll 1
        for (int j = 0; j < CLEN; ++j) {
            uint32_t wj = sm.ps.w[j * 256 + c];
            float dx = __uint_as_float(wj << 16);
            float uy = __uint_as_float(wj & 0xffff0000u);
            float dA[NN];
            #pragma unroll
            for (int nn = 0; nn < NN; ++nn) dA[nn] = __builtin_amdgcn_exp2f(A2[nn] * dx);
            float yv = 0.f;
            #pragma unroll
            for (int nn = 0; nn < NN; ++nn) {
                float Bu = uy * sm.ps.bm[j * 16 + nn];
                h[nn] = fmaf(dA[nn], h[nn], Bu);
                yv = fmaf(h[nn], sm.ps.cm[j * 16 + nn], yv);
            }
            yC[((size_t)b1 * LL + p0 + inner * j) * CC + c] = 0.25f * yv;
        }
    }

    gbar(bar + 3);   // yAB/yC visible

    // ================= Phase E: k6 transpose-reduce =================
    {
        int pt  = blockIdx.x & 63;
        int ct6 = (blockIdx.x >> 6) & 3;
        int b6  = blockIdx.x >> 8;
        int p06 = pt * 64, c06 = ct6 * 64;
        {
            int cl = t & 63;
            int pg = t >> 6;
            #pragma unroll
            for (int pp = 0; pp < 16; ++pp) {
                int pl = pp * 4 + pg;
                size_t ix = ((size_t)b6 * LL + p06 + pl) * CC + c06 + cl;
                sm.tile[cl * 65 + pl] = yAB[ix] + yC[ix];
            }
        }
        __syncthreads();
        {
            int pl = t & 63;
            int cg6 = t >> 6;
            #pragma unroll
            for (int cc = 0; cc < 16; ++cc) {
                int cloc = cc * 4 + cg6;
                int c6 = c06 + cloc;
                size_t o = ((size_t)b6 * CC + c6) * LL + p06 + pl;
                out[o] = sm.tile[cloc * 65 + pl] + feat[o] * Dv[c6];
            }
        }
    }
}

extern "C" void kernel_launch(void* const* d_in, const int* in_sizes, int n_in,
                              void* d_out, int out_size, void* d_ws, size_t ws_size,
                              hipStream_t stream)
{
    const float* feat  = (const float*)d_in[0];
    const float* A_log = (const float*)d_in[1];
    const float* Dv    = (const float*)d_in[2];
    const float* Wd    = (const float*)d_in[3];
    const float* bd    = (const float*)d_in[4];
    const float* WB    = (const float*)d_in[5];
    const float* WC    = (const float*)d_in[6];
    float* out = (float*)d_out;

    float* ws  = (float*)d_ws;
    uint32_t* du = (uint32_t*)ws;                         //  2,097,152 u32 (bf16x2)
    float* Bm  = ws  + (size_t)2097152;                   //    131,072
    float* Cm  = Bm  + (size_t)131072;                    //    131,072
    float* P   = Cm  + (size_t)131072;                    //  3,145,728
    float* S   = P   + (size_t)3145728;                   //  3,145,728
    float* Hin = S   + (size_t)3145728;                   //  4,194,304
    float* yAB = Hin + (size_t)4194304;                   //  2,097,152
    float* yC  = yAB + (size_t)2097152;                   //  2,097,152
    uint32_t* bar = (uint32_t*)(yC + (size_t)2097152);    //  4 barrier counters

    hipMemsetAsync(bar, 0, 4 * sizeof(uint32_t), stream); // captured -> resets each replay

    fused_all<<<NBLK, 256, 0, stream>>>(
        feat, A_log, Dv, Wd, bd, WB, WC, out,
        du, Bm, Cm, P, S, Hin, yAB, yC, bar);
}

// Round 12
// 151.227 us; speedup vs baseline: 2.4160x; 2.4160x over previous
//
#include <hip/hip_runtime.h>
#include <cstdint>
#include <cstddef>

#define BB 2
#define CC 256
#define NN 16
#define LL 4096
#define NCH 128
#define CLEN 32
#define LOG2E 1.4426950408889634f

typedef __attribute__((ext_vector_type(8))) short short8;
typedef __attribute__((ext_vector_type(4))) float f32x4;

__device__ __forceinline__ float softplus_f(float z) {
    return fmaxf(z, 0.f) + log1pf(expf(-fabsf(z)));
}

__device__ __forceinline__ uint32_t pack_bf2(float d, float u) {
    uint32_t lo = (__float_as_uint(d) + 0x8000u) >> 16;
    uint32_t hh = (__float_as_uint(u) + 0x8000u) & 0xffff0000u;
    return hh | lo;
}

__device__ __forceinline__ short bf16r(float f) {
    return (short)((__float_as_uint(f) + 0x8000u) >> 16);
}

// ---------------- K1 (MFMA): Z = X@Wd via bf16 matrix cores -----------------
// R6-measured version (direct global fragment loads; R7's LDS variant was
// neutral-to-worse: staging bank conflicts, see R11 fused profile 6.9M).
__global__ __launch_bounds__(256) void k1_mfma(
    const float* __restrict__ feat, const float* __restrict__ Wd,
    const float* __restrict__ bd, const float* __restrict__ WB,
    const float* __restrict__ WC, uint32_t* __restrict__ du,
    float* __restrict__ Bm, float* __restrict__ Cm)
{
    int blk = blockIdx.x;               // b*512 + lt*4 + ct
    int b  = blk >> 9;
    int lt = (blk >> 2) & 127;
    int ct = blk & 3;
    int l0 = lt * 32, c0 = ct * 64;
    const float* fbase = feat + (size_t)b * CC * LL;
    int lane = threadIdx.x & 63;
    int wq   = threadIdx.x >> 6;
    int m    = lane & 15;
    int quad = lane >> 4;
    int m0   = (wq & 1) * 16;
    int n0   = (wq >> 1) * 32;
    bool doBC = (ct == 0);
    const float* wBC = (wq >> 1) ? WC : WB;

    f32x4 acc0 = {0.f, 0.f, 0.f, 0.f};
    f32x4 acc1 = {0.f, 0.f, 0.f, 0.f};
    f32x4 accB = {0.f, 0.f, 0.f, 0.f};

    const float* aptr  = fbase + (size_t)(quad * 8) * LL + (l0 + m0 + m);
    const float* b0ptr = Wd    + (size_t)(quad * 8) * CC + (c0 + n0 + m);
    const float* b1ptr = b0ptr + 16;
    const float* bbptr = wBC   + (size_t)(quad * 8) * NN + m;

    for (int ks = 0; ks < 8; ++ks) {
        short8 af, bf0, bf1;
        #pragma unroll
        for (int j = 0; j < 8; ++j) {
            size_t kr = (size_t)(ks * 32 + j);
            af[j]  = bf16r(aptr [kr * LL]);
            bf0[j] = bf16r(b0ptr[kr * CC]);
            bf1[j] = bf16r(b1ptr[kr * CC]);
        }
        acc0 = __builtin_amdgcn_mfma_f32_16x16x32_bf16(af, bf0, acc0, 0, 0, 0);
        acc1 = __builtin_amdgcn_mfma_f32_16x16x32_bf16(af, bf1, acc1, 0, 0, 0);
        if (doBC) {
            short8 bbf;
            #pragma unroll
            for (int j = 0; j < 8; ++j)
                bbf[j] = bf16r(bbptr[(size_t)(ks * 32 + j) * NN]);
            accB = __builtin_amdgcn_mfma_f32_16x16x32_bf16(af, bbf, accB, 0, 0, 0);
        }
    }

    if (doBC) {
        float* dst = (wq >> 1) ? Cm : Bm;
        #pragma unroll
        for (int r = 0; r < 4; ++r) {
            int l = l0 + m0 + quad * 4 + r;
            dst[((size_t)b * LL + l) * NN + m] = accB[r];
        }
    }

    float bd0 = bd[c0 + n0 + m];
    float bd1 = bd[c0 + n0 + 16 + m];
    int cA = c0 + n0 + m;
    int cB = cA + 16;
    #pragma unroll
    for (int r = 0; r < 4; ++r) {
        int l = l0 + m0 + quad * 4 + r;
        float d0 = softplus_f(acc0[r] + bd0);
        float d1 = softplus_f(acc1[r] + bd1);
        float x0 = fbase[(size_t)cA * LL + l];
        float x1 = fbase[(size_t)cB * LL + l];
        du[((size_t)b * LL + l) * CC + cA] = pack_bf2(d0, d0 * x0);
        du[((size_t)b * LL + l) * CC + cB] = pack_bf2(d1, d1 * x1);
    }
}

// ---------------- P1: per-chunk aggregates, nn-SPLIT ------------------------
// R12 delta: P/S have no cross-nn coupling, so split the 16-state scan
// across two threads (nn 0-7 / 8-15): 512-thread blocks, thread=(ch,half).
// Doubles waves/CU 8->16 (LDS 34KB -> 2 blocks/CU capacity holds) and
// halves each thread's serial exp2/fma span. sW staged by half 0 only;
// one barrier covers sBm+sW sharing.
__global__ __launch_bounds__(512) void p1_aggr(
    const uint32_t* __restrict__ du, const float* __restrict__ Bm,
    const float* __restrict__ A_log, float* __restrict__ P, float* __restrict__ S)
{
    int blk = blockIdx.x;
    int b  = (blk >> 7) & 1;
    int ch = blk & 127;
    int t = threadIdx.x;       // 0..511
    int c = t & 255;           // channel
    int nb = (t >> 8) * 8;     // nn base: 0 or 8
    __shared__ float sBm[CLEN * NN];
    __shared__ uint32_t sW[CLEN * 256];

    float A2[8];
    {
        const float4* al = (const float4*)(A_log + c * NN + nb);
        #pragma unroll
        for (int q = 0; q < 2; ++q) {
            float4 v = al[q];
            A2[q*4+0] = -expf(v.x) * LOG2E;
            A2[q*4+1] = -expf(v.y) * LOG2E;
            A2[q*4+2] = -expf(v.z) * LOG2E;
            A2[q*4+3] = -expf(v.w) * LOG2E;
        }
    }

    int p0, inner;
    if (blk < 256) { p0 = 32 * ch;                          inner = 1;  }
    else           { p0 = 63 - (ch >> 1) + 2048 * (ch & 1); inner = 64; }

    {   // sBm: 512 elements, 512 threads -> exactly one each
        int j = t >> 4, nn = t & 15;
        sBm[t] = Bm[((size_t)b * LL + (p0 + inner * j)) * NN + nn];
    }
    if (t < 256) {   // half 0 stages sW for its channel
        const uint32_t* dub = du + (size_t)b * LL * CC + c;
        uint32_t wt[CLEN];
        #pragma unroll
        for (int j = 0; j < CLEN; ++j) wt[j] = dub[(size_t)(p0 + inner * j) * CC];
        #pragma unroll
        for (int j = 0; j < CLEN; ++j) sW[j * 256 + c] = wt[j];
    }
    __syncthreads();

    if (blk < 256) {
        float Sf[8] = {}, Sr[8] = {}, pref[8];
        #pragma unroll
        for (int nn = 0; nn < 8; ++nn) pref[nn] = 1.f;
        float sumd = 0.f;
        #pragma unroll 1
        for (int j = 0; j < CLEN; ++j) {
            uint32_t wj = sW[j * 256 + c];
            float dx = __uint_as_float(wj << 16);
            float uy = __uint_as_float(wj & 0xffff0000u);
            sumd += dx;
            float dA[8];
            #pragma unroll
            for (int nn = 0; nn < 8; ++nn) dA[nn] = __builtin_amdgcn_exp2f(A2[nn] * dx);
            #pragma unroll
            for (int nn = 0; nn < 8; ++nn) {
                float Bu = uy * sBm[j * 16 + nb + nn];
                Sf[nn] = fmaf(dA[nn], Sf[nn], Bu);
                Sr[nn] = fmaf(pref[nn], Bu, Sr[nn]);
                pref[nn] *= dA[nn];
            }
        }
        size_t base0 = ((size_t)(b * 128 + ch)) * 4096 + (size_t)c * 16 + nb;
        size_t base1 = ((size_t)((2 + b) * 128 + (127 - ch))) * 4096 + (size_t)c * 16 + nb;
        #pragma unroll
        for (int nn = 0; nn < 8; ++nn) {
            P[base0 + nn] = __builtin_amdgcn_exp2f(A2[nn] * sumd);
            S[base0 + nn] = Sf[nn];
            S[base1 + nn] = Sr[nn];
        }
    } else {
        float Sv[8] = {};
        float sumd = 0.f;
        #pragma unroll 1
        for (int j = 0; j < CLEN; ++j) {
            uint32_t wj = sW[j * 256 + c];
            float dx = __uint_as_float(wj << 16);
            float uy = __uint_as_float(wj & 0xffff0000u);
            sumd += dx;
            float dA[8];
            #pragma unroll
            for (int nn = 0; nn < 8; ++nn) dA[nn] = __builtin_amdgcn_exp2f(A2[nn] * dx);
            #pragma unroll
            for (int nn = 0; nn < 8; ++nn)
                Sv[nn] = fmaf(dA[nn], Sv[nn], uy * sBm[j * 16 + nb + nn]);
        }
        size_t base = ((size_t)((4 + b) * 128 + ch)) * 4096 + (size_t)c * 16 + nb;
        #pragma unroll
        for (int nn = 0; nn < 8; ++nn) {
            P[base + nn] = __builtin_amdgcn_exp2f(A2[nn] * sumd);
            S[base + nn] = Sv[nn];
        }
    }
}

// ---------------- P2: scan chunk aggregates per direction -> Hin ------------
__global__ __launch_bounds__(128) void p2_scan(
    const float* __restrict__ P, const float* __restrict__ S, float* __restrict__ Hin)
{
    int r = blockIdx.x * 128 + threadIdx.x;   // 32768 rows
    int cn = r & 4095;
    int db = r >> 12;
    int d = db >> 1;
    int cls = (d == 1) ? 1 : ((d == 3) ? 2 : 0);
    int b = db & 1;
    const size_t sbase = ((size_t)(cls * 2 + b) * 128) * 4096 + cn;
    const size_t pbase = (d == 1) ? (((size_t)b * 128) * 4096 + cn) : sbase;
    const size_t obase = ((size_t)db * 128) * 4096 + cn;
    float h = 0.f;
    for (int g = 0; g < 16; ++g) {
        float pv[8], sv[8];
        #pragma unroll
        for (int i = 0; i < 8; ++i) {
            int ch = g * 8 + i;
            int chm = (d == 2) ? (126 - 2 * (ch >> 1) + (ch & 1)) : ch;
            int chp = (d == 1) ? (127 - ch) : chm;
            pv[i] = P[pbase + (size_t)chp * 4096];
            sv[i] = S[sbase + (size_t)chm * 4096];
        }
        #pragma unroll
        for (int i = 0; i < 8; ++i) {
            Hin[obase + (size_t)(g * 8 + i) * 4096] = h;
            h = fmaf(pv[i], h, sv[i]);
        }
    }
}

// ---------------- P3: replay (R6-measured version, unchanged) ---------------
__global__ __launch_bounds__(256) void p3_replay(
    const uint32_t* __restrict__ du, const float* __restrict__ Bm,
    const float* __restrict__ Cm, const float* __restrict__ A_log,
    const float* __restrict__ Hin, float* __restrict__ yAB,
    float* __restrict__ yC)
{
    int blk = blockIdx.x;
    int b  = (blk >> 7) & 1;
    int ch = blk & 127;
    int c = threadIdx.x;
    __shared__ float sBm[CLEN * NN];
    __shared__ float sCm[CLEN * NN];
    __shared__ uint32_t sW[CLEN * 256];
    __shared__ float sY[CLEN * 256];

    float A2[NN];
    {
        const float4* al = (const float4*)(A_log + c * NN);
        #pragma unroll
        for (int q = 0; q < 4; ++q) {
            float4 v = al[q];
            A2[q*4+0] = -expf(v.x) * LOG2E;
            A2[q*4+1] = -expf(v.y) * LOG2E;
            A2[q*4+2] = -expf(v.z) * LOG2E;
            A2[q*4+3] = -expf(v.w) * LOG2E;
        }
    }

    if (blk < 256) {
        int p0 = 32 * ch;
        for (int i = threadIdx.x; i < CLEN * NN; i += 256) {
            int j = i >> 4, nn = i & 15;
            size_t o = ((size_t)b * LL + (p0 + j)) * NN + nn;
            sBm[i] = Bm[o];
            sCm[i] = Cm[o];
        }
        const uint32_t* dub = du + (size_t)b * LL * CC + c;
        {
            uint32_t wt[CLEN];
            #pragma unroll
            for (int j = 0; j < CLEN; ++j) wt[j] = dub[(size_t)(p0 + j) * CC];
            #pragma unroll
            for (int j = 0; j < CLEN; ++j) sW[j * 256 + c] = wt[j];
        }

        // --- backward pass: d1 (l decreasing == j 31..0); only h1 live ---
        int chr = 127 - ch;                     // d1 chunk covering same l-set
        float h1[NN];
        {
            const float4* hp1 = (const float4*)(Hin + ((size_t)(1 * 2 + b) * 128 + chr) * 4096 + (size_t)c * 16);
            #pragma unroll
            for (int q = 0; q < 4; ++q) {
                float4 v1 = hp1[q];
                h1[q*4+0]=v1.x; h1[q*4+1]=v1.y; h1[q*4+2]=v1.z; h1[q*4+3]=v1.w;
            }
        }
        __syncthreads();    // sBm/sCm cooperative load complete
        #pragma unroll 1
        for (int j = CLEN - 1; j >= 0; --j) {
            uint32_t wj = sW[j * 256 + c];
            float dx = __uint_as_float(wj << 16);
            float uy = __uint_as_float(wj & 0xffff0000u);
            float dA[NN];
            #pragma unroll
            for (int nn = 0; nn < NN; ++nn) dA[nn] = __builtin_amdgcn_exp2f(A2[nn] * dx);
            float yv = 0.f;
            #pragma unroll
            for (int nn = 0; nn < NN; ++nn) {
                float Bu = uy * sBm[j * 16 + nn];
                h1[nn] = fmaf(dA[nn], h1[nn], Bu);
                yv = fmaf(h1[nn], sCm[j * 16 + nn], yv);
            }
            sY[j * 256 + c] = yv;    // own slot; no barrier needed
        }

        // --- forward pass: d0 + d2; h1 dead, load h0/h2 now ---
        int ch2 = 126 - (ch & ~1) + (ch & 1);   // d2 scan-position of this chunk
        float h0[NN], h2[NN];
        {
            const float4* hp0 = (const float4*)(Hin + ((size_t)(0 * 2 + b) * 128 + ch)  * 4096 + (size_t)c * 16);
            const float4* hp2 = (const float4*)(Hin + ((size_t)(2 * 2 + b) * 128 + ch2) * 4096 + (size_t)c * 16);
            #pragma unroll
            for (int q = 0; q < 4; ++q) {
                float4 v0 = hp0[q], v2 = hp2[q];
                h0[q*4+0]=v0.x; h0[q*4+1]=v0.y; h0[q*4+2]=v0.z; h0[q*4+3]=v0.w;
                h2[q*4+0]=v2.x; h2[q*4+1]=v2.y; h2[q*4+2]=v2.z; h2[q*4+3]=v2.w;
            }
        }
        #pragma unroll 1
        for (int j = 0; j < CLEN; ++j) {
            uint32_t wj = sW[j * 256 + c];
            float dx = __uint_as_float(wj << 16);
            float uy = __uint_as_float(wj & 0xffff0000u);
            float dA[NN];
            #pragma unroll
            for (int nn = 0; nn < NN; ++nn) dA[nn] = __builtin_amdgcn_exp2f(A2[nn] * dx);
            float y0v = 0.f, y2v = 0.f;
            #pragma unroll
            for (int nn = 0; nn < NN; ++nn) {
                float Bu = uy * sBm[j * 16 + nn];
                float cm = sCm[j * 16 + nn];
                h0[nn] = fmaf(dA[nn], h0[nn], Bu);
                h2[nn] = fmaf(dA[nn], h2[nn], Bu);
                y0v = fmaf(h0[nn], cm, y0v);
                y2v = fmaf(h2[nn], cm, y2v);
            }
            yAB[((size_t)b * LL + p0 + j) * CC + c] = 0.25f * (y0v + y2v + sY[j * 256 + c]);
        }
    } else {
        // d3 column replay
        int p0 = 63 - (ch >> 1) + 2048 * (ch & 1);
        const int inner = 64;
        for (int i = threadIdx.x; i < CLEN * NN; i += 256) {
            int j = i >> 4, nn = i & 15;
            size_t o = ((size_t)b * LL + (p0 + inner * j)) * NN + nn;
            sBm[i] = Bm[o];
            sCm[i] = Cm[o];
        }
        const uint32_t* dub = du + (size_t)b * LL * CC + c;
        {
            uint32_t wt[CLEN];
            #pragma unroll
            for (int j = 0; j < CLEN; ++j) wt[j] = dub[(size_t)(p0 + inner * j) * CC];
            #pragma unroll
            for (int j = 0; j < CLEN; ++j) sW[j * 256 + c] = wt[j];
        }
        float h[NN];
        {
            const float4* hp = (const float4*)(Hin + ((size_t)(3 * 2 + b) * 128 + ch) * 4096 + (size_t)c * 16);
            #pragma unroll
            for (int q = 0; q < 4; ++q) {
                float4 v = hp[q];
                h[q*4+0]=v.x; h[q*4+1]=v.y; h[q*4+2]=v.z; h[q*4+3]=v.w;
            }
        }
        __syncthreads();
        #pragma unroll 1
        for (int j = 0; j < CLEN; ++j) {
            uint32_t wj = sW[j * 256 + c];
            float dx = __uint_as_float(wj << 16);
            float uy = __uint_as_float(wj & 0xffff0000u);
            float dA[NN];
            #pragma unroll
            for (int nn = 0; nn < NN; ++nn) dA[nn] = __builtin_amdgcn_exp2f(A2[nn] * dx);
            float yv = 0.f;
            #pragma unroll
            for (int nn = 0; nn < NN; ++nn) {
                float Bu = uy * sBm[j * 16 + nn];
                h[nn] = fmaf(dA[nn], h[nn], Bu);
                yv = fmaf(h[nn], sCm[j * 16 + nn], yv);
            }
            yC[((size_t)b * LL + p0 + inner * j) * CC + c] = 0.25f * yv;
        }
    }
}

// ---------------- K6: sum 2 y-buffers + x*D, transpose to (B,C,L) -----------
__global__ __launch_bounds__(256) void k6_reduce(
    const float* __restrict__ feat, const float* __restrict__ D,
    const float* __restrict__ yAB, const float* __restrict__ yC,
    float* __restrict__ out)
{
    int pt = blockIdx.x & 63;
    int ct = (blockIdx.x >> 6) & 3;
    int b  = blockIdx.x >> 8;
    int p0 = pt * 64, c0 = ct * 64;
    __shared__ float tile[64 * 65];
    {
        int cl = threadIdx.x & 63;
        int pg = threadIdx.x >> 6;
        #pragma unroll
        for (int pp = 0; pp < 16; ++pp) {
            int pl = pp * 4 + pg;
            size_t ix = ((size_t)b * LL + p0 + pl) * CC + c0 + cl;
            tile[cl * 65 + pl] = yAB[ix] + yC[ix];
        }
    }
    __syncthreads();
    {
        int pl = threadIdx.x & 63;
        int cg = threadIdx.x >> 6;
        #pragma unroll
        for (int cc = 0; cc < 16; ++cc) {
            int cloc = cc * 4 + cg;
            int c = c0 + cloc;
            size_t o = ((size_t)b * CC + c) * LL + p0 + pl;
            out[o] = tile[cloc * 65 + pl] + feat[o] * D[c];
        }
    }
}

extern "C" void kernel_launch(void* const* d_in, const int* in_sizes, int n_in,
                              void* d_out, int out_size, void* d_ws, size_t ws_size,
                              hipStream_t stream)
{
    const float* feat  = (const float*)d_in[0];
    const float* A_log = (const float*)d_in[1];
    const float* D     = (const float*)d_in[2];
    const float* Wd    = (const float*)d_in[3];
    const float* bd    = (const float*)d_in[4];
    const float* WB    = (const float*)d_in[5];
    const float* WC    = (const float*)d_in[6];
    float* out = (float*)d_out;

    float* ws  = (float*)d_ws;
    uint32_t* du = (uint32_t*)ws;                         //  2,097,152 u32 (bf16x2)
    float* Bm  = ws  + (size_t)2097152;                   //    131,072
    float* Cm  = Bm  + (size_t)131072;                    //    131,072
    float* P   = Cm  + (size_t)131072;                    //  3,145,728 (3 cls; cls1 P unused)
    float* S   = P   + (size_t)3145728;                   //  3,145,728
    float* Hin = S   + (size_t)3145728;                   //  4,194,304 (4 dirs)
    float* yAB = Hin + (size_t)4194304;                   //  2,097,152
    float* yC  = yAB + (size_t)2097152;                   //  2,097,152

    k1_mfma<<<1024, 256, 0, stream>>>(feat, Wd, bd, WB, WC, du, Bm, Cm);
    p1_aggr<<<512, 512, 0, stream>>>(du, Bm, A_log, P, S);
    p2_scan<<<256, 128, 0, stream>>>(P, S, Hin);
    p3_replay<<<512, 256, 0, stream>>>(du, Bm, Cm, A_log, Hin, yAB, yC);
    k6_reduce<<<512, 256, 0, stream>>>(feat, D, yAB, yC, out);
}